// Round 1
// baseline (199.841 us; speedup 1.0000x reference)
//
#include <hip/hip_runtime.h>
#include <hip/hip_bf16.h>

#define N_NODES 4096
#define F_IN    512
#define HC      512   // H*C
#define H_HEADS 8
#define C_DIM   64
#define NCLS    16
#define CAP     192   // max neighbors/row; Binomial(4096,0.01) max ~<100 w.p. 1-1e-30
#define NEG_SLOPE 0.2f

// ---------------- CSR build from dense adj (adds self loop) ----------------
__global__ __launch_bounds__(256) void k_build_csr(const float* __restrict__ adj,
                                                   int* __restrict__ row_cnt,
                                                   int* __restrict__ col_idx) {
    int i = blockIdx.x;
    int t = threadIdx.x;
    __shared__ int cnt_s;
    if (t == 0) cnt_s = 0;
    __syncthreads();
    const float4* row = (const float4*)(adj + (size_t)i * N_NODES);
    int* cols = col_idx + (size_t)i * CAP;
#pragma unroll
    for (int it = 0; it < 4; ++it) {
        int idx4 = it * 256 + t;
        float4 v = row[idx4];
        int j0 = idx4 * 4;
        if (v.x != 0.f && j0 + 0 != i) { int p = atomicAdd(&cnt_s, 1); if (p < CAP - 1) cols[p] = j0 + 0; }
        if (v.y != 0.f && j0 + 1 != i) { int p = atomicAdd(&cnt_s, 1); if (p < CAP - 1) cols[p] = j0 + 1; }
        if (v.z != 0.f && j0 + 2 != i) { int p = atomicAdd(&cnt_s, 1); if (p < CAP - 1) cols[p] = j0 + 2; }
        if (v.w != 0.f && j0 + 3 != i) { int p = atomicAdd(&cnt_s, 1); if (p < CAP - 1) cols[p] = j0 + 3; }
    }
    __syncthreads();
    if (t == 0) {
        int p = min(cnt_s, CAP - 1);
        cols[p] = i;                 // self loop (diag forced to 1 by reference)
        row_cnt[i] = p + 1;
    }
}

// ---------------- GEMM1: h1 = x @ W1, fp32, 64x64 tile, 4x4/thread ----------------
#define BM 64
#define BN 64
#define BK 16
__global__ __launch_bounds__(256) void k_gemm1(const float* __restrict__ A,   // [4096,512]
                                               const float* __restrict__ B,   // [512,512]
                                               float* __restrict__ C) {       // [4096,512]
    __shared__ float As[BK][BM + 4];
    __shared__ float Bs[BK][BN + 4];
    int t = threadIdx.x;
    int tx = t & 15, ty = t >> 4;
    int m0 = blockIdx.y * BM;
    int n0 = blockIdx.x * BN;
    float acc[4][4] = {};
    int arow = t >> 2;           // 0..63
    int akc  = (t & 3) * 4;      // 0,4,8,12
    int brow = t >> 4;           // 0..15
    int bnc  = (t & 15) * 4;
    for (int k0 = 0; k0 < F_IN; k0 += BK) {
        float4 av = *(const float4*)&A[(size_t)(m0 + arow) * F_IN + k0 + akc];
        float4 bv = *(const float4*)&B[(size_t)(k0 + brow) * HC + n0 + bnc];
        As[akc + 0][arow] = av.x;
        As[akc + 1][arow] = av.y;
        As[akc + 2][arow] = av.z;
        As[akc + 3][arow] = av.w;
        *(float4*)&Bs[brow][bnc] = bv;
        __syncthreads();
#pragma unroll
        for (int k = 0; k < BK; ++k) {
            float4 a = *(const float4*)&As[k][ty * 4];
            float4 b = *(const float4*)&Bs[k][tx * 4];
            float aa[4] = {a.x, a.y, a.z, a.w};
            float bb[4] = {b.x, b.y, b.z, b.w};
#pragma unroll
            for (int mi = 0; mi < 4; ++mi)
#pragma unroll
                for (int ni = 0; ni < 4; ++ni)
                    acc[mi][ni] += aa[mi] * bb[ni];
        }
        __syncthreads();
    }
#pragma unroll
    for (int mi = 0; mi < 4; ++mi) {
        float4 v = make_float4(acc[mi][0], acc[mi][1], acc[mi][2], acc[mi][3]);
        *(float4*)&C[(size_t)(m0 + ty * 4 + mi) * HC + n0 + tx * 4] = v;
    }
}

// ---------------- per-node attention scalars, layer 1 ----------------
__global__ __launch_bounds__(256) void k_attn1(const float* __restrict__ hf,
                                               const float* __restrict__ att_src,
                                               const float* __restrict__ att_dst,
                                               float* __restrict__ a_src,
                                               float* __restrict__ a_dst) {
    int i = blockIdx.x;
    int t = threadIdx.x;
    int lane = t & 63;
    int w = t >> 6;
#pragma unroll
    for (int half = 0; half < 2; ++half) {
        int e = half * 256 + w * 64 + lane;    // one wave == one head's 64 channels
        float v = hf[(size_t)i * HC + e];
        float s = v * att_src[e];
        float d = v * att_dst[e];
#pragma unroll
        for (int o = 32; o > 0; o >>= 1) {
            s += __shfl_down(s, o, 64);
            d += __shfl_down(d, o, 64);
        }
        if (lane == 0) {
            int h = e >> 6;
            a_src[i * H_HEADS + h] = s;
            a_dst[i * H_HEADS + h] = d;
        }
    }
}

// ---------------- layer-1 softmax aggregation + bias + ELU ----------------
__global__ __launch_bounds__(256) void k_agg1(const float* __restrict__ hf,
                                              const float* __restrict__ a_src,
                                              const float* __restrict__ a_dst,
                                              const int* __restrict__ row_cnt,
                                              const int* __restrict__ col_idx,
                                              const float* __restrict__ b1,
                                              float* __restrict__ elu1) {
    int i = blockIdx.x;
    int t = threadIdx.x;
    __shared__ float wL[CAP][H_HEADS];
    __shared__ int   colL[CAP];
    __shared__ float denom[H_HEADS];
    __shared__ float ad[H_HEADS];
    int cnt = row_cnt[i];
    if (t < H_HEADS) ad[t] = a_dst[i * H_HEADS + t];
    for (int j = t; j < cnt; j += 256) colL[j] = col_idx[(size_t)i * CAP + j];
    __syncthreads();
    for (int idx = t; idx < cnt * H_HEADS; idx += 256) {
        int j = idx >> 3, h = idx & 7;
        float l = a_src[colL[j] * H_HEADS + h] + ad[h];
        l = (l > 0.f) ? l : NEG_SLOPE * l;    // logits are O(1); exp w/o max-shift is safe
        wL[j][h] = __expf(l);
    }
    __syncthreads();
    if (t < H_HEADS) {
        float s = 0.f;
        for (int j = 0; j < cnt; ++j) s += wL[j][t];
        denom[t] = s;
    }
    __syncthreads();
    float acc0 = 0.f, acc1 = 0.f;
    int e0 = t, e1 = t + 256;
    int h0 = e0 >> 6, h1 = e1 >> 6;
    for (int j = 0; j < cnt; ++j) {
        int col = colL[j];
        const float* rowp = hf + (size_t)col * HC;
        acc0 += wL[j][h0] * rowp[e0];
        acc1 += wL[j][h1] * rowp[e1];
    }
    float o0 = acc0 / denom[h0] + b1[e0];
    float o1 = acc1 / denom[h1] + b1[e1];
    o0 = (o0 > 0.f) ? o0 : (__expf(o0) - 1.f);   // ELU
    o1 = (o1 > 0.f) ? o1 : (__expf(o1) - 1.f);
    elu1[(size_t)i * HC + e0] = o0;
    elu1[(size_t)i * HC + e1] = o1;
}

// ---------------- GEMM2 + layer-2 attention scalars, one node/block ----------------
__global__ __launch_bounds__(256) void k_gemm2(const float* __restrict__ elu1,
                                               const float* __restrict__ W2,   // [512,16]
                                               const float* __restrict__ att_src2,
                                               const float* __restrict__ att_dst2,
                                               float* __restrict__ h2,
                                               float* __restrict__ a_src2,
                                               float* __restrict__ a_dst2) {
    int i = blockIdx.x;
    int t = threadIdx.x;
    __shared__ float row[HC];
    __shared__ float part[16][NCLS];
    __shared__ float h2row[NCLS];
    *(float2*)&row[t * 2] = *(const float2*)&elu1[(size_t)i * HC + t * 2];
    __syncthreads();
    int c = t & 15, p = t >> 4;
    float s = 0.f;
#pragma unroll 8
    for (int ks = 0; ks < 32; ++ks) {
        int k = p * 32 + ks;
        s += row[k] * W2[k * NCLS + c];
    }
    part[p][c] = s;
    __syncthreads();
    if (t < NCLS) {
        float v = 0.f;
#pragma unroll
        for (int pp = 0; pp < 16; ++pp) v += part[pp][t];
        h2[(size_t)i * NCLS + t] = v;
        h2row[t] = v;
    }
    __syncthreads();
    if (t == 0) {
        float ssum = 0.f, dsum = 0.f;
#pragma unroll
        for (int cc = 0; cc < NCLS; ++cc) {
            ssum += h2row[cc] * att_src2[cc];
            dsum += h2row[cc] * att_dst2[cc];
        }
        a_src2[i] = ssum;
        a_dst2[i] = dsum;
    }
}

// ---------------- layer-2 softmax aggregation (one wave/node) + bias ----------------
__global__ __launch_bounds__(256) void k_agg2(const float* __restrict__ h2,
                                              const float* __restrict__ a_src2,
                                              const float* __restrict__ a_dst2,
                                              const int* __restrict__ row_cnt,
                                              const int* __restrict__ col_idx,
                                              const float* __restrict__ b2,
                                              float* __restrict__ out) {
    int t = threadIdx.x;
    int w = t >> 6, lane = t & 63;
    int i = blockIdx.x * 4 + w;
    __shared__ float ew[4][CAP];
    __shared__ int   colL[4][CAP];
    int cnt = row_cnt[i];
    float adi = a_dst2[i];
    float sum = 0.f;
    for (int j = lane; j < cnt; j += 64) {
        int col = col_idx[(size_t)i * CAP + j];
        colL[w][j] = col;
        float l = a_src2[col] + adi;
        l = (l > 0.f) ? l : NEG_SLOPE * l;
        float e = __expf(l);
        ew[w][j] = e;
        sum += e;
    }
#pragma unroll
    for (int o = 32; o > 0; o >>= 1) sum += __shfl_down(sum, o, 64);
    float dnm = __shfl(sum, 0, 64);
    __syncthreads();
    if (lane < NCLS) {
        float acc = 0.f;
        for (int j = 0; j < cnt; ++j)
            acc += ew[w][j] * h2[(size_t)colL[w][j] * NCLS + lane];
        out[(size_t)i * NCLS + lane] = acc / dnm + b2[lane];
    }
}

extern "C" void kernel_launch(void* const* d_in, const int* in_sizes, int n_in,
                              void* d_out, int out_size, void* d_ws, size_t ws_size,
                              hipStream_t stream) {
    const float* x        = (const float*)d_in[0];
    const float* adj      = (const float*)d_in[1];
    const float* W1       = (const float*)d_in[2];
    const float* att_src1 = (const float*)d_in[3];
    const float* att_dst1 = (const float*)d_in[4];
    const float* b1       = (const float*)d_in[5];
    const float* W2       = (const float*)d_in[6];
    const float* att_src2 = (const float*)d_in[7];
    const float* att_dst2 = (const float*)d_in[8];
    const float* b2       = (const float*)d_in[9];
    float* out = (float*)d_out;

    char* ws = (char*)d_ws;
    int*   row_cnt = (int*)ws;            ws += (size_t)N_NODES * 4;
    int*   col_idx = (int*)ws;            ws += (size_t)N_NODES * CAP * 4;
    float* h1      = (float*)ws;          ws += (size_t)N_NODES * HC * 4;
    float* a_src   = (float*)ws;          ws += (size_t)N_NODES * H_HEADS * 4;
    float* a_dst   = (float*)ws;          ws += (size_t)N_NODES * H_HEADS * 4;
    float* elu1    = (float*)ws;          ws += (size_t)N_NODES * HC * 4;
    float* h2      = (float*)ws;          ws += (size_t)N_NODES * NCLS * 4;
    float* as2     = (float*)ws;          ws += (size_t)N_NODES * 4;
    float* ad2     = (float*)ws;          ws += (size_t)N_NODES * 4;
    // total ~20.6 MB of d_ws

    hipLaunchKernelGGL(k_build_csr, dim3(N_NODES), dim3(256), 0, stream, adj, row_cnt, col_idx);
    hipLaunchKernelGGL(k_gemm1, dim3(HC / BN, N_NODES / BM), dim3(256), 0, stream, x, W1, h1);
    hipLaunchKernelGGL(k_attn1, dim3(N_NODES), dim3(256), 0, stream, h1, att_src1, att_dst1, a_src, a_dst);
    hipLaunchKernelGGL(k_agg1, dim3(N_NODES), dim3(256), 0, stream, h1, a_src, a_dst, row_cnt, col_idx, b1, elu1);
    hipLaunchKernelGGL(k_gemm2, dim3(N_NODES), dim3(256), 0, stream, elu1, W2, att_src2, att_dst2, h2, as2, ad2);
    hipLaunchKernelGGL(k_agg2, dim3(N_NODES / 4), dim3(256), 0, stream, h2, as2, ad2, row_cnt, col_idx, b2, out);
}

// Round 2
// 192.432 us; speedup vs baseline: 1.0385x; 1.0385x over previous
//
#include <hip/hip_runtime.h>
#include <hip/hip_bf16.h>

#define N_NODES 4096
#define F_IN    512
#define HC      512   // H*C
#define H_HEADS 8
#define C_DIM   64
#define NCLS    16
#define CAP     192
#define NEG_SLOPE 0.2f

typedef __bf16 bf16x8 __attribute__((ext_vector_type(8)));
typedef float  f32x4  __attribute__((ext_vector_type(4)));
typedef unsigned short us8 __attribute__((ext_vector_type(8)));

// ---------------- CSR build from dense adj (adds self loop) ----------------
__global__ __launch_bounds__(256) void k_build_csr(const float* __restrict__ adj,
                                                   int* __restrict__ row_cnt,
                                                   int* __restrict__ col_idx) {
    int i = blockIdx.x;
    int t = threadIdx.x;
    __shared__ int cnt_s;
    if (t == 0) cnt_s = 0;
    __syncthreads();
    const float4* row = (const float4*)(adj + (size_t)i * N_NODES);
    int* cols = col_idx + (size_t)i * CAP;
#pragma unroll
    for (int it = 0; it < 4; ++it) {
        int idx4 = it * 256 + t;
        float4 v = row[idx4];
        int j0 = idx4 * 4;
        if (v.x != 0.f && j0 + 0 != i) { int p = atomicAdd(&cnt_s, 1); if (p < CAP - 1) cols[p] = j0 + 0; }
        if (v.y != 0.f && j0 + 1 != i) { int p = atomicAdd(&cnt_s, 1); if (p < CAP - 1) cols[p] = j0 + 1; }
        if (v.z != 0.f && j0 + 2 != i) { int p = atomicAdd(&cnt_s, 1); if (p < CAP - 1) cols[p] = j0 + 2; }
        if (v.w != 0.f && j0 + 3 != i) { int p = atomicAdd(&cnt_s, 1); if (p < CAP - 1) cols[p] = j0 + 3; }
    }
    __syncthreads();
    if (t == 0) {
        int p = min(cnt_s, CAP - 1);
        cols[p] = i;                 // self loop
        row_cnt[i] = p + 1;
    }
}

// ---------------- split x into bf16 hi/lo ----------------
__global__ __launch_bounds__(256) void k_split_x(const float* __restrict__ x,
                                                 ushort* __restrict__ hi,
                                                 ushort* __restrict__ lo) {
    int idx = (blockIdx.x * 256 + threadIdx.x) * 4;
    float4 v = *(const float4*)&x[idx];
    float f[4] = {v.x, v.y, v.z, v.w};
    ushort4 hv, lv;
    unsigned short* hp = &hv.x;
    unsigned short* lp = &lv.x;
#pragma unroll
    for (int u = 0; u < 4; ++u) {
        __bf16 h = (__bf16)f[u];
        __bf16 l = (__bf16)(f[u] - (float)h);
        hp[u] = __builtin_bit_cast(unsigned short, h);
        lp[u] = __builtin_bit_cast(unsigned short, l);
    }
    *(ushort4*)&hi[idx] = hv;
    *(ushort4*)&lo[idx] = lv;
}

// ---------------- split + transpose W1 -> [N][K] bf16 hi/lo ----------------
__global__ __launch_bounds__(256) void k_split_wT(const float* __restrict__ W,   // [512k][512n]
                                                  ushort* __restrict__ hiT,      // [n][k]
                                                  ushort* __restrict__ loT) {
    __shared__ float tile[64][65];
    int t = threadIdx.x;
    int n0 = blockIdx.x * 64, k0 = blockIdx.y * 64;
#pragma unroll
    for (int i = 0; i < 4; ++i) {
        int r = i * 16 + (t >> 4);
        int c = (t & 15) * 4;
        *(float4*)&tile[r][c] = *(const float4*)&W[(size_t)(k0 + r) * HC + n0 + c];
    }
    __syncthreads();
#pragma unroll
    for (int i = 0; i < 4; ++i) {
        int n = i * 16 + (t >> 4);
        int k4 = (t & 15) * 4;
        ushort4 hv, lv;
        unsigned short* hp = &hv.x;
        unsigned short* lp = &lv.x;
#pragma unroll
        for (int u = 0; u < 4; ++u) {
            float f = tile[k4 + u][n];
            __bf16 h = (__bf16)f;
            __bf16 l = (__bf16)(f - (float)h);
            hp[u] = __builtin_bit_cast(unsigned short, h);
            lp[u] = __builtin_bit_cast(unsigned short, l);
        }
        *(ushort4*)&hiT[(size_t)(n0 + n) * F_IN + k0 + k4] = hv;
        *(ushort4*)&loT[(size_t)(n0 + n) * F_IN + k0 + k4] = lv;
    }
}

// ---------------- GEMM1 via bf16 MFMA, 3-pass hi/lo split ----------------
// 64x64 tile, BK=32, 4 waves each 32x32 (2x2 of 16x16x32 MFMA).
// LDS layout per array: [rowgroup g][lane*8 ushort] — lane-linear so
// global_load_lds (lane*16B) and fragment ds_read_b128 are both natural.
__global__ __launch_bounds__(256) void k_gemm1(const ushort* __restrict__ Ahi,
                                               const ushort* __restrict__ Alo,
                                               const ushort* __restrict__ Bhi,
                                               const ushort* __restrict__ Blo,
                                               float* __restrict__ C) {
    __shared__ __align__(16) ushort smem[4][2048];   // 4 arrays x 4KB
    int t = threadIdx.x;
    int w = t >> 6, lane = t & 63;
    int n0 = blockIdx.x * 64;
    int m0 = blockIdx.y * 64;
    const ushort* src = (w == 0) ? Ahi : (w == 1) ? Alo : (w == 2) ? Bhi : Blo;
    int rb = ((w < 2) ? m0 : n0) + (lane & 15);
    int kcol = (lane >> 4) * 8;
    int mw = (w & 1) * 32, nw = (w >> 1) * 32;
    f32x4 acc[2][2] = {};
    for (int k0 = 0; k0 < F_IN; k0 += 32) {
#pragma unroll
        for (int g = 0; g < 4; ++g) {
            const ushort* gp = src + (size_t)(rb + g * 16) * F_IN + k0 + kcol;
            __builtin_amdgcn_global_load_lds(
                (const __attribute__((address_space(1))) void*)gp,
                (__attribute__((address_space(3))) void*)&smem[w][g * 512],
                16, 0, 0);
        }
        __syncthreads();
        bf16x8 ahi[2], alo[2], bhi[2], blo[2];
#pragma unroll
        for (int mi = 0; mi < 2; ++mi) {
            int g = (mw >> 4) + mi;
            ahi[mi] = __builtin_bit_cast(bf16x8, *(const us8*)&smem[0][g * 512 + lane * 8]);
            alo[mi] = __builtin_bit_cast(bf16x8, *(const us8*)&smem[1][g * 512 + lane * 8]);
        }
#pragma unroll
        for (int ni = 0; ni < 2; ++ni) {
            int g = (nw >> 4) + ni;
            bhi[ni] = __builtin_bit_cast(bf16x8, *(const us8*)&smem[2][g * 512 + lane * 8]);
            blo[ni] = __builtin_bit_cast(bf16x8, *(const us8*)&smem[3][g * 512 + lane * 8]);
        }
#pragma unroll
        for (int mi = 0; mi < 2; ++mi)
#pragma unroll
            for (int ni = 0; ni < 2; ++ni) {
                acc[mi][ni] = __builtin_amdgcn_mfma_f32_16x16x32_bf16(ahi[mi], bhi[ni], acc[mi][ni], 0, 0, 0);
                acc[mi][ni] = __builtin_amdgcn_mfma_f32_16x16x32_bf16(alo[mi], bhi[ni], acc[mi][ni], 0, 0, 0);
                acc[mi][ni] = __builtin_amdgcn_mfma_f32_16x16x32_bf16(ahi[mi], blo[ni], acc[mi][ni], 0, 0, 0);
            }
        __syncthreads();
    }
    int r0 = (lane >> 4) * 4;
    int cn = lane & 15;
#pragma unroll
    for (int mi = 0; mi < 2; ++mi)
#pragma unroll
        for (int ni = 0; ni < 2; ++ni) {
            size_t base = (size_t)(m0 + mw + mi * 16 + r0) * HC + (n0 + nw + ni * 16 + cn);
#pragma unroll
            for (int r = 0; r < 4; ++r)
                C[base + (size_t)r * HC] = acc[mi][ni][r];
        }
}

// ---------------- per-node attention scalars, layer 1 ----------------
__global__ __launch_bounds__(256) void k_attn1(const float* __restrict__ hf,
                                               const float* __restrict__ att_src,
                                               const float* __restrict__ att_dst,
                                               float* __restrict__ a_src,
                                               float* __restrict__ a_dst) {
    int i = blockIdx.x;
    int t = threadIdx.x;
    int lane = t & 63;
    int w = t >> 6;
#pragma unroll
    for (int half = 0; half < 2; ++half) {
        int e = half * 256 + w * 64 + lane;
        float v = hf[(size_t)i * HC + e];
        float s = v * att_src[e];
        float d = v * att_dst[e];
#pragma unroll
        for (int o = 32; o > 0; o >>= 1) {
            s += __shfl_down(s, o, 64);
            d += __shfl_down(d, o, 64);
        }
        if (lane == 0) {
            int h = e >> 6;
            a_src[i * H_HEADS + h] = s;
            a_dst[i * H_HEADS + h] = d;
        }
    }
}

// ---------------- layer-1 softmax aggregation + bias + ELU ----------------
__global__ __launch_bounds__(256) void k_agg1(const float* __restrict__ hf,
                                              const float* __restrict__ a_src,
                                              const float* __restrict__ a_dst,
                                              const int* __restrict__ row_cnt,
                                              const int* __restrict__ col_idx,
                                              const float* __restrict__ b1,
                                              float* __restrict__ elu1) {
    int i = blockIdx.x;
    int t = threadIdx.x;
    __shared__ float wL[CAP][H_HEADS];
    __shared__ int   colL[CAP];
    __shared__ float denom[H_HEADS];
    __shared__ float ad[H_HEADS];
    int cnt = row_cnt[i];
    if (t < H_HEADS) ad[t] = a_dst[i * H_HEADS + t];
    for (int j = t; j < cnt; j += 256) colL[j] = col_idx[(size_t)i * CAP + j];
    __syncthreads();
    for (int idx = t; idx < cnt * H_HEADS; idx += 256) {
        int j = idx >> 3, h = idx & 7;
        float l = a_src[colL[j] * H_HEADS + h] + ad[h];
        l = (l > 0.f) ? l : NEG_SLOPE * l;
        wL[j][h] = __expf(l);
    }
    __syncthreads();
    if (t < H_HEADS) {
        float s = 0.f;
        for (int j = 0; j < cnt; ++j) s += wL[j][t];
        denom[t] = s;
    }
    __syncthreads();
    int e = t * 2;
    int h = e >> 6;
    float ax = 0.f, ay = 0.f;
    int j = 0;
    for (; j + 4 <= cnt; j += 4) {
        int c0 = colL[j], c1 = colL[j + 1], c2 = colL[j + 2], c3 = colL[j + 3];
        float2 v0 = *(const float2*)&hf[(size_t)c0 * HC + e];
        float2 v1 = *(const float2*)&hf[(size_t)c1 * HC + e];
        float2 v2 = *(const float2*)&hf[(size_t)c2 * HC + e];
        float2 v3 = *(const float2*)&hf[(size_t)c3 * HC + e];
        float w0 = wL[j][h], w1 = wL[j + 1][h], w2 = wL[j + 2][h], w3 = wL[j + 3][h];
        ax += w0 * v0.x + w1 * v1.x + w2 * v2.x + w3 * v3.x;
        ay += w0 * v0.y + w1 * v1.y + w2 * v2.y + w3 * v3.y;
    }
    for (; j < cnt; ++j) {
        int c0 = colL[j];
        float2 v0 = *(const float2*)&hf[(size_t)c0 * HC + e];
        float w0 = wL[j][h];
        ax += w0 * v0.x;
        ay += w0 * v0.y;
    }
    float inv = 1.f / denom[h];
    float o0 = ax * inv + b1[e];
    float o1 = ay * inv + b1[e + 1];
    o0 = (o0 > 0.f) ? o0 : (__expf(o0) - 1.f);
    o1 = (o1 > 0.f) ? o1 : (__expf(o1) - 1.f);
    float2 ov = make_float2(o0, o1);
    *(float2*)&elu1[(size_t)i * HC + e] = ov;
}

// ---------------- GEMM2 (16 nodes/block, W2 in LDS) + layer-2 scalars ----------------
__global__ __launch_bounds__(256) void k_gemm2(const float* __restrict__ elu1,
                                               const float* __restrict__ W2,     // [512,16]
                                               const float* __restrict__ att_src2,
                                               const float* __restrict__ att_dst2,
                                               float* __restrict__ h2,
                                               float* __restrict__ a_src2,
                                               float* __restrict__ a_dst2) {
    __shared__ float W2s[HC * NCLS];   // 32 KB
    __shared__ float h2s[16][NCLS];
    int t = threadIdx.x;
    int n0 = blockIdx.x * 16;
#pragma unroll
    for (int u = 0; u < 8; ++u) {
        int idx = (u * 256 + t) * 4;
        *(float4*)&W2s[idx] = *(const float4*)&W2[idx];
    }
    __syncthreads();
    int nl = t >> 4, c = t & 15;
    const float* row = elu1 + (size_t)(n0 + nl) * HC;
    float acc = 0.f;
    for (int k = 0; k < HC; k += 4) {
        float4 v = *(const float4*)&row[k];
        acc += v.x * W2s[(k + 0) * NCLS + c] + v.y * W2s[(k + 1) * NCLS + c]
             + v.z * W2s[(k + 2) * NCLS + c] + v.w * W2s[(k + 3) * NCLS + c];
    }
    h2[(size_t)(n0 + nl) * NCLS + c] = acc;
    h2s[nl][c] = acc;
    __syncthreads();
    if (t < 16) {
        float s = 0.f, d = 0.f;
#pragma unroll
        for (int cc = 0; cc < NCLS; ++cc) {
            s += h2s[t][cc] * att_src2[cc];
            d += h2s[t][cc] * att_dst2[cc];
        }
        a_src2[n0 + t] = s;
        a_dst2[n0 + t] = d;
    }
}

// ---------------- layer-2 softmax aggregation, all 64 lanes used ----------------
__global__ __launch_bounds__(256) void k_agg2(const float* __restrict__ h2,
                                              const float* __restrict__ a_src2,
                                              const float* __restrict__ a_dst2,
                                              const int* __restrict__ row_cnt,
                                              const int* __restrict__ col_idx,
                                              const float* __restrict__ b2,
                                              float* __restrict__ out) {
    int t = threadIdx.x;
    int w = t >> 6, lane = t & 63;
    int i = blockIdx.x * 4 + w;
    __shared__ float ew[4][CAP];
    __shared__ int   colL[4][CAP];
    int cnt = row_cnt[i];
    float adi = a_dst2[i];
    float sum = 0.f;
    for (int j = lane; j < cnt; j += 64) {
        int col = col_idx[(size_t)i * CAP + j];
        colL[w][j] = col;
        float l = a_src2[col] + adi;
        l = (l > 0.f) ? l : NEG_SLOPE * l;
        float e = __expf(l);
        ew[w][j] = e;
        sum += e;
    }
#pragma unroll
    for (int o = 32; o > 0; o >>= 1) sum += __shfl_xor(sum, o, 64);
    // same-wave LDS produce/consume: no barrier needed
    int q = lane >> 4, c = lane & 15;
    float acc = 0.f;
    for (int j = q; j < cnt; j += 4)
        acc += ew[w][j] * h2[(size_t)colL[w][j] * NCLS + c];
    acc += __shfl_down(acc, 32, 64);
    acc += __shfl_down(acc, 16, 64);
    if (lane < NCLS)
        out[(size_t)i * NCLS + lane] = acc / sum + b2[lane];
}

extern "C" void kernel_launch(void* const* d_in, const int* in_sizes, int n_in,
                              void* d_out, int out_size, void* d_ws, size_t ws_size,
                              hipStream_t stream) {
    const float* x        = (const float*)d_in[0];
    const float* adj      = (const float*)d_in[1];
    const float* W1       = (const float*)d_in[2];
    const float* att_src1 = (const float*)d_in[3];
    const float* att_dst1 = (const float*)d_in[4];
    const float* b1       = (const float*)d_in[5];
    const float* W2       = (const float*)d_in[6];
    const float* att_src2 = (const float*)d_in[7];
    const float* att_dst2 = (const float*)d_in[8];
    const float* b2       = (const float*)d_in[9];
    float* out = (float*)d_out;

    char* ws = (char*)d_ws;
    int*    row_cnt = (int*)ws;     ws += (size_t)N_NODES * 4;
    int*    col_idx = (int*)ws;     ws += (size_t)N_NODES * CAP * 4;
    float*  h1      = (float*)ws;   ws += (size_t)N_NODES * HC * 4;
    float*  a_src   = (float*)ws;   ws += (size_t)N_NODES * H_HEADS * 4;
    float*  a_dst   = (float*)ws;   ws += (size_t)N_NODES * H_HEADS * 4;
    float*  elu1    = (float*)ws;   ws += (size_t)N_NODES * HC * 4;
    float*  h2      = (float*)ws;   ws += (size_t)N_NODES * NCLS * 4;
    float*  as2     = (float*)ws;   ws += (size_t)N_NODES * 4;
    float*  ad2     = (float*)ws;   ws += (size_t)N_NODES * 4;
    ushort* x_hi    = (ushort*)ws;  ws += (size_t)N_NODES * F_IN * 2;
    ushort* x_lo    = (ushort*)ws;  ws += (size_t)N_NODES * F_IN * 2;
    ushort* w_hiT   = (ushort*)ws;  ws += (size_t)F_IN * HC * 2;
    ushort* w_loT   = (ushort*)ws;  ws += (size_t)F_IN * HC * 2;
    // total ~30 MB of d_ws

    hipLaunchKernelGGL(k_split_x, dim3(N_NODES * F_IN / 1024), dim3(256), 0, stream, x, x_hi, x_lo);
    hipLaunchKernelGGL(k_split_wT, dim3(8, 8), dim3(256), 0, stream, W1, w_hiT, w_loT);
    hipLaunchKernelGGL(k_build_csr, dim3(N_NODES), dim3(256), 0, stream, adj, row_cnt, col_idx);
    hipLaunchKernelGGL(k_gemm1, dim3(HC / 64, N_NODES / 64), dim3(256), 0, stream, x_hi, x_lo, w_hiT, w_loT, h1);
    hipLaunchKernelGGL(k_attn1, dim3(N_NODES), dim3(256), 0, stream, h1, att_src1, att_dst1, a_src, a_dst);
    hipLaunchKernelGGL(k_agg1, dim3(N_NODES), dim3(256), 0, stream, h1, a_src, a_dst, row_cnt, col_idx, b1, elu1);
    hipLaunchKernelGGL(k_gemm2, dim3(N_NODES / 16), dim3(256), 0, stream, elu1, W2, att_src2, att_dst2, h2, as2, ad2);
    hipLaunchKernelGGL(k_agg2, dim3(N_NODES / 4), dim3(256), 0, stream, h2, as2, ad2, row_cnt, col_idx, b2, out);
}

// Round 4
// 171.992 us; speedup vs baseline: 1.1619x; 1.1188x over previous
//
#include <hip/hip_runtime.h>
#include <hip/hip_bf16.h>
#include <hip/hip_fp16.h>

#define N_NODES 4096
#define F_IN    512
#define HC      512   // H*C
#define H_HEADS 8
#define C_DIM   64
#define NCLS    16
#define CAP     192
#define NEG_SLOPE 0.2f

typedef __bf16 bf16x8 __attribute__((ext_vector_type(8)));
typedef float  f32x4  __attribute__((ext_vector_type(4)));
typedef unsigned short us8 __attribute__((ext_vector_type(8)));

// Staged operand layout for gemm1: array of 1KB chunks, chunk(rg,kb) at
// ushort offset (rg*16+kb)*512; lane l within chunk holds 8 ushorts for
// row rg*16+(l&15), k = kb*32 + (l>>4)*8 .. +8.  global_load_lds stages
// chunk_base + lane*16B (coalesced, lane-linear) and the LDS image is
// exactly the MFMA A/B fragment order -> conflict-free ds_read_b128.

// ---------------- CSR build from dense adj (adds self loop) ----------------
__global__ __launch_bounds__(256) void k_build_csr(const float* __restrict__ adj,
                                                   int* __restrict__ row_cnt,
                                                   int* __restrict__ col_idx) {
    int i = blockIdx.x;
    int t = threadIdx.x;
    __shared__ int cnt_s;
    if (t == 0) cnt_s = 0;
    __syncthreads();
    const float4* row = (const float4*)(adj + (size_t)i * N_NODES);
    int* cols = col_idx + (size_t)i * CAP;
#pragma unroll
    for (int it = 0; it < 4; ++it) {
        int idx4 = it * 256 + t;
        float4 v = row[idx4];
        int j0 = idx4 * 4;
        if (v.x != 0.f && j0 + 0 != i) { int p = atomicAdd(&cnt_s, 1); if (p < CAP - 1) cols[p] = j0 + 0; }
        if (v.y != 0.f && j0 + 1 != i) { int p = atomicAdd(&cnt_s, 1); if (p < CAP - 1) cols[p] = j0 + 1; }
        if (v.z != 0.f && j0 + 2 != i) { int p = atomicAdd(&cnt_s, 1); if (p < CAP - 1) cols[p] = j0 + 2; }
        if (v.w != 0.f && j0 + 3 != i) { int p = atomicAdd(&cnt_s, 1); if (p < CAP - 1) cols[p] = j0 + 3; }
    }
    __syncthreads();
    if (t == 0) {
        int p = min(cnt_s, CAP - 1);
        cols[p] = i;                 // self loop
        row_cnt[i] = p + 1;
    }
}

// ---------------- split x into bf16 hi/lo, staged layout ----------------
__global__ __launch_bounds__(256) void k_split_x(const float* __restrict__ x,
                                                 ushort* __restrict__ hi,
                                                 ushort* __restrict__ lo) {
    int tid = blockIdx.x * 256 + threadIdx.x;      // one 16B chunk slot
    int rg = tid >> 10;                            // 1024 slots per 16-row group
    int c  = tid & 1023;
    int kb = c >> 6;
    int l  = c & 63;
    int row = rg * 16 + (l & 15);
    int kbase = kb * 32 + (l >> 4) * 8;
    const float* src = &x[(size_t)row * F_IN + kbase];
    float4 v0 = *(const float4*)&src[0];
    float4 v1 = *(const float4*)&src[4];
    float f[8] = {v0.x, v0.y, v0.z, v0.w, v1.x, v1.y, v1.z, v1.w};
    us8 hv, lv;
#pragma unroll
    for (int u = 0; u < 8; ++u) {
        __bf16 h = (__bf16)f[u];
        __bf16 lo_ = (__bf16)(f[u] - (float)h);
        hv[u] = __builtin_bit_cast(unsigned short, h);
        lv[u] = __builtin_bit_cast(unsigned short, lo_);
    }
    *(us8*)&hi[(size_t)tid * 8] = hv;
    *(us8*)&lo[(size_t)tid * 8] = lv;
}

// ---------------- split + transpose W1 -> staged layout (n as "row") ----------------
__global__ __launch_bounds__(256) void k_split_wT(const float* __restrict__ W,   // [512k][512n]
                                                  ushort* __restrict__ hiT,
                                                  ushort* __restrict__ loT) {
    __shared__ float tile[64][65];                 // [k_local][n_local]
    int t = threadIdx.x;
    int n0 = blockIdx.x * 64, k0 = blockIdx.y * 64;
#pragma unroll
    for (int i = 0; i < 4; ++i) {
        int r = i * 16 + (t >> 4);
        int c = (t & 15) * 4;
        *(float4*)&tile[r][c] = *(const float4*)&W[(size_t)(k0 + r) * HC + n0 + c];
    }
    __syncthreads();
    int rg_local = t >> 6;
    int l = t & 63;
    int n_local = rg_local * 16 + (l & 15);
#pragma unroll
    for (int kb_local = 0; kb_local < 2; ++kb_local) {
        int k_local = kb_local * 32 + (l >> 4) * 8;
        us8 hv, lv;
#pragma unroll
        for (int u = 0; u < 8; ++u) {
            float f = tile[k_local + u][n_local];
            __bf16 h = (__bf16)f;
            __bf16 lo_ = (__bf16)(f - (float)h);
            hv[u] = __builtin_bit_cast(unsigned short, h);
            lv[u] = __builtin_bit_cast(unsigned short, lo_);
        }
        int rg = (n0 >> 4) + rg_local;
        int kb = (k0 >> 5) + kb_local;
        size_t off = ((size_t)(rg * 16 + kb) * 64 + l) * 8;
        *(us8*)&hiT[off] = hv;
        *(us8*)&loT[off] = lv;
    }
}

// ---------------- GEMM1 via bf16 MFMA (3-pass hi/lo), fp16 output ----------------
__global__ __launch_bounds__(256) void k_gemm1(const ushort* __restrict__ Ahi,
                                               const ushort* __restrict__ Alo,
                                               const ushort* __restrict__ Bhi,
                                               const ushort* __restrict__ Blo,
                                               __half* __restrict__ C) {
    __shared__ __align__(16) ushort smem[4][2048];   // 4 arrays x 4KB
    int t = threadIdx.x;
    int w = t >> 6, lane = t & 63;
    int n0 = blockIdx.x * 64;
    int m0 = blockIdx.y * 64;
    const ushort* src = (w == 0) ? Ahi : (w == 1) ? Alo : (w == 2) ? Bhi : Blo;
    int rg0 = ((w < 2) ? m0 : n0) >> 4;
    int mw = (w & 1) * 32, nw = (w >> 1) * 32;
    f32x4 acc[2][2] = {};
    for (int kb = 0; kb < 16; ++kb) {
#pragma unroll
        for (int g = 0; g < 4; ++g) {
            // per-lane: lane reads its own 16B of the 1KB chunk
            const ushort* gp = src + ((size_t)((rg0 + g) * 16 + kb) * 64 + lane) * 8;
            __builtin_amdgcn_global_load_lds(
                (const __attribute__((address_space(1))) void*)gp,
                (__attribute__((address_space(3))) void*)&smem[w][g * 512],
                16, 0, 0);
        }
        __syncthreads();
        bf16x8 ahi[2], alo[2], bhi[2], blo[2];
#pragma unroll
        for (int mi = 0; mi < 2; ++mi) {
            int g = (mw >> 4) + mi;
            ahi[mi] = __builtin_bit_cast(bf16x8, *(const us8*)&smem[0][g * 512 + lane * 8]);
            alo[mi] = __builtin_bit_cast(bf16x8, *(const us8*)&smem[1][g * 512 + lane * 8]);
        }
#pragma unroll
        for (int ni = 0; ni < 2; ++ni) {
            int g = (nw >> 4) + ni;
            bhi[ni] = __builtin_bit_cast(bf16x8, *(const us8*)&smem[2][g * 512 + lane * 8]);
            blo[ni] = __builtin_bit_cast(bf16x8, *(const us8*)&smem[3][g * 512 + lane * 8]);
        }
#pragma unroll
        for (int mi = 0; mi < 2; ++mi)
#pragma unroll
            for (int ni = 0; ni < 2; ++ni) {
                acc[mi][ni] = __builtin_amdgcn_mfma_f32_16x16x32_bf16(ahi[mi], bhi[ni], acc[mi][ni], 0, 0, 0);
                acc[mi][ni] = __builtin_amdgcn_mfma_f32_16x16x32_bf16(alo[mi], bhi[ni], acc[mi][ni], 0, 0, 0);
                acc[mi][ni] = __builtin_amdgcn_mfma_f32_16x16x32_bf16(ahi[mi], blo[ni], acc[mi][ni], 0, 0, 0);
            }
        __syncthreads();
    }
    int r0 = (lane >> 4) * 4;
    int cn = lane & 15;
#pragma unroll
    for (int mi = 0; mi < 2; ++mi)
#pragma unroll
        for (int ni = 0; ni < 2; ++ni) {
            size_t base = (size_t)(m0 + mw + mi * 16 + r0) * HC + (n0 + nw + ni * 16 + cn);
#pragma unroll
            for (int r = 0; r < 4; ++r)
                C[base + (size_t)r * HC] = __float2half(acc[mi][ni][r]);
        }
}

// ---------------- per-node attention scalars, layer 1 (fp16 h1) ----------------
__global__ __launch_bounds__(256) void k_attn1(const __half* __restrict__ hf,
                                               const float* __restrict__ att_src,
                                               const float* __restrict__ att_dst,
                                               float* __restrict__ a_src,
                                               float* __restrict__ a_dst) {
    int i = blockIdx.x;
    int t = threadIdx.x;
    int lane = t & 63;
    int w = t >> 6;
#pragma unroll
    for (int half = 0; half < 2; ++half) {
        int e = half * 256 + w * 64 + lane;
        float v = __half2float(hf[(size_t)i * HC + e]);
        float s = v * att_src[e];
        float d = v * att_dst[e];
#pragma unroll
        for (int o = 32; o > 0; o >>= 1) {
            s += __shfl_down(s, o, 64);
            d += __shfl_down(d, o, 64);
        }
        if (lane == 0) {
            int h = e >> 6;
            a_src[i * H_HEADS + h] = s;
            a_dst[i * H_HEADS + h] = d;
        }
    }
}

// ---------------- layer-1 softmax aggregation + bias + ELU ----------------
__global__ __launch_bounds__(256) void k_agg1(const __half* __restrict__ hf,
                                              const float* __restrict__ a_src,
                                              const float* __restrict__ a_dst,
                                              const int* __restrict__ row_cnt,
                                              const int* __restrict__ col_idx,
                                              const float* __restrict__ b1,
                                              float* __restrict__ elu1) {
    int i = blockIdx.x;
    int t = threadIdx.x;
    __shared__ float wL[CAP][H_HEADS];
    __shared__ int   colL[CAP];
    __shared__ float denom[H_HEADS];
    __shared__ float ad[H_HEADS];
    int cnt = row_cnt[i];
    if (t < H_HEADS) ad[t] = a_dst[i * H_HEADS + t];
    for (int j = t; j < cnt; j += 256) colL[j] = col_idx[(size_t)i * CAP + j];
    __syncthreads();
    for (int idx = t; idx < cnt * H_HEADS; idx += 256) {
        int j = idx >> 3, h = idx & 7;
        float l = a_src[colL[j] * H_HEADS + h] + ad[h];
        l = (l > 0.f) ? l : NEG_SLOPE * l;
        wL[j][h] = __expf(l);
    }
    __syncthreads();
    if (t < H_HEADS) {
        float s = 0.f;
        for (int j = 0; j < cnt; ++j) s += wL[j][t];
        denom[t] = s;
    }
    __syncthreads();
    int e = t * 2;
    int h = e >> 6;
    float ax = 0.f, ay = 0.f;
    int j = 0;
    for (; j + 4 <= cnt; j += 4) {
        int c0 = colL[j], c1 = colL[j + 1], c2 = colL[j + 2], c3 = colL[j + 3];
        float2 v0 = __half22float2(*(const __half2*)&hf[(size_t)c0 * HC + e]);
        float2 v1 = __half22float2(*(const __half2*)&hf[(size_t)c1 * HC + e]);
        float2 v2 = __half22float2(*(const __half2*)&hf[(size_t)c2 * HC + e]);
        float2 v3 = __half22float2(*(const __half2*)&hf[(size_t)c3 * HC + e]);
        float w0 = wL[j][h], w1 = wL[j + 1][h], w2 = wL[j + 2][h], w3 = wL[j + 3][h];
        ax += w0 * v0.x + w1 * v1.x + w2 * v2.x + w3 * v3.x;
        ay += w0 * v0.y + w1 * v1.y + w2 * v2.y + w3 * v3.y;
    }
    for (; j < cnt; ++j) {
        int c0 = colL[j];
        float2 v0 = __half22float2(*(const __half2*)&hf[(size_t)c0 * HC + e]);
        float w0 = wL[j][h];
        ax += w0 * v0.x;
        ay += w0 * v0.y;
    }
    float inv = 1.f / denom[h];
    float o0 = ax * inv + b1[e];
    float o1 = ay * inv + b1[e + 1];
    o0 = (o0 > 0.f) ? o0 : (__expf(o0) - 1.f);
    o1 = (o1 > 0.f) ? o1 : (__expf(o1) - 1.f);
    float2 ov = make_float2(o0, o1);
    *(float2*)&elu1[(size_t)i * HC + e] = ov;
}

// ---------------- GEMM2 (16 nodes/block, W2 in LDS) + layer-2 scalars ----------------
__global__ __launch_bounds__(256) void k_gemm2(const float* __restrict__ elu1,
                                               const float* __restrict__ W2,     // [512,16]
                                               const float* __restrict__ att_src2,
                                               const float* __restrict__ att_dst2,
                                               float* __restrict__ h2,
                                               float* __restrict__ a_src2,
                                               float* __restrict__ a_dst2) {
    __shared__ float W2s[HC * NCLS];   // 32 KB
    __shared__ float h2s[16][NCLS];
    int t = threadIdx.x;
    int n0 = blockIdx.x * 16;
#pragma unroll
    for (int u = 0; u < 8; ++u) {
        int idx = (u * 256 + t) * 4;
        *(float4*)&W2s[idx] = *(const float4*)&W2[idx];
    }
    __syncthreads();
    int nl = t >> 4, c = t & 15;
    const float* row = elu1 + (size_t)(n0 + nl) * HC;
    float acc = 0.f;
    for (int k = 0; k < HC; k += 4) {
        float4 v = *(const float4*)&row[k];
        acc += v.x * W2s[(k + 0) * NCLS + c] + v.y * W2s[(k + 1) * NCLS + c]
             + v.z * W2s[(k + 2) * NCLS + c] + v.w * W2s[(k + 3) * NCLS + c];
    }
    h2[(size_t)(n0 + nl) * NCLS + c] = acc;
    h2s[nl][c] = acc;
    __syncthreads();
    if (t < 16) {
        float s = 0.f, d = 0.f;
#pragma unroll
        for (int cc = 0; cc < NCLS; ++cc) {
            s += h2s[t][cc] * att_src2[cc];
            d += h2s[t][cc] * att_dst2[cc];
        }
        a_src2[n0 + t] = s;
        a_dst2[n0 + t] = d;
    }
}

// ---------------- layer-2 softmax aggregation, all 64 lanes used ----------------
__global__ __launch_bounds__(256) void k_agg2(const float* __restrict__ h2,
                                              const float* __restrict__ a_src2,
                                              const float* __restrict__ a_dst2,
                                              const int* __restrict__ row_cnt,
                                              const int* __restrict__ col_idx,
                                              const float* __restrict__ b2,
                                              float* __restrict__ out) {
    int t = threadIdx.x;
    int w = t >> 6, lane = t & 63;
    int i = blockIdx.x * 4 + w;
    __shared__ float ew[4][CAP];
    __shared__ int   colL[4][CAP];
    int cnt = row_cnt[i];
    float adi = a_dst2[i];
    float sum = 0.f;
    for (int j = lane; j < cnt; j += 64) {
        int col = col_idx[(size_t)i * CAP + j];
        colL[w][j] = col;
        float l = a_src2[col] + adi;
        l = (l > 0.f) ? l : NEG_SLOPE * l;
        float e = __expf(l);
        ew[w][j] = e;
        sum += e;
    }
#pragma unroll
    for (int o = 32; o > 0; o >>= 1) sum += __shfl_xor(sum, o, 64);
    int q = lane >> 4, c = lane & 15;
    float acc = 0.f;
    for (int j = q; j < cnt; j += 4)
        acc += ew[w][j] * h2[(size_t)colL[w][j] * NCLS + c];
    acc += __shfl_down(acc, 32, 64);
    acc += __shfl_down(acc, 16, 64);
    if (lane < NCLS)
        out[(size_t)i * NCLS + lane] = acc / sum + b2[lane];
}

extern "C" void kernel_launch(void* const* d_in, const int* in_sizes, int n_in,
                              void* d_out, int out_size, void* d_ws, size_t ws_size,
                              hipStream_t stream) {
    const float* x        = (const float*)d_in[0];
    const float* adj      = (const float*)d_in[1];
    const float* W1       = (const float*)d_in[2];
    const float* att_src1 = (const float*)d_in[3];
    const float* att_dst1 = (const float*)d_in[4];
    const float* b1       = (const float*)d_in[5];
    const float* W2       = (const float*)d_in[6];
    const float* att_src2 = (const float*)d_in[7];
    const float* att_dst2 = (const float*)d_in[8];
    const float* b2       = (const float*)d_in[9];
    float* out = (float*)d_out;

    char* ws = (char*)d_ws;
    int*    row_cnt = (int*)ws;     ws += (size_t)N_NODES * 4;
    int*    col_idx = (int*)ws;     ws += (size_t)N_NODES * CAP * 4;
    __half* h1f     = (__half*)ws;  ws += (size_t)N_NODES * HC * 2;
    float*  a_src   = (float*)ws;   ws += (size_t)N_NODES * H_HEADS * 4;
    float*  a_dst   = (float*)ws;   ws += (size_t)N_NODES * H_HEADS * 4;
    float*  elu1    = (float*)ws;   ws += (size_t)N_NODES * HC * 4;
    float*  h2      = (float*)ws;   ws += (size_t)N_NODES * NCLS * 4;
    float*  as2     = (float*)ws;   ws += (size_t)N_NODES * 4;
    float*  ad2     = (float*)ws;   ws += (size_t)N_NODES * 4;
    ushort* x_hi    = (ushort*)ws;  ws += (size_t)N_NODES * F_IN * 2;
    ushort* x_lo    = (ushort*)ws;  ws += (size_t)N_NODES * F_IN * 2;
    ushort* w_hiT   = (ushort*)ws;  ws += (size_t)F_IN * HC * 2;
    ushort* w_loT   = (ushort*)ws;  ws += (size_t)F_IN * HC * 2;

    hipLaunchKernelGGL(k_split_x, dim3(N_NODES * F_IN / (256 * 8)), dim3(256), 0, stream, x, x_hi, x_lo);
    hipLaunchKernelGGL(k_split_wT, dim3(8, 8), dim3(256), 0, stream, W1, w_hiT, w_loT);
    hipLaunchKernelGGL(k_build_csr, dim3(N_NODES), dim3(256), 0, stream, adj, row_cnt, col_idx);
    hipLaunchKernelGGL(k_gemm1, dim3(HC / 64, N_NODES / 64), dim3(256), 0, stream, x_hi, x_lo, w_hiT, w_loT, h1f);
    hipLaunchKernelGGL(k_attn1, dim3(N_NODES), dim3(256), 0, stream, h1f, att_src1, att_dst1, a_src, a_dst);
    hipLaunchKernelGGL(k_agg1, dim3(N_NODES), dim3(256), 0, stream, h1f, a_src, a_dst, row_cnt, col_idx, b1, elu1);
    hipLaunchKernelGGL(k_gemm2, dim3(N_NODES / 16), dim3(256), 0, stream, elu1, W2, att_src2, att_dst2, h2, as2, ad2);
    hipLaunchKernelGGL(k_agg2, dim3(N_NODES / 4), dim3(256), 0, stream, h2, as2, ad2, row_cnt, col_idx, b2, out);
}

// Round 6
// 165.234 us; speedup vs baseline: 1.2094x; 1.0409x over previous
//
#include <hip/hip_runtime.h>
#include <hip/hip_bf16.h>
#include <hip/hip_fp16.h>

#define N_NODES 4096
#define F_IN    512
#define HC      512   // H*C
#define H_HEADS 8
#define C_DIM   64
#define NCLS    16
#define CAP     192
#define NEG_SLOPE 0.2f

typedef __bf16 bf16x8 __attribute__((ext_vector_type(8)));
typedef float  f32x4  __attribute__((ext_vector_type(4)));
typedef unsigned short us8 __attribute__((ext_vector_type(8)));

// Staged operand layout for gemm1: array of 1KB chunks, chunk(rg,kb) at
// ushort offset (rg*16+kb)*512; lane l holds 8 ushorts for row rg*16+(l&15),
// k = kb*32+(l>>4)*8.  global_load_lds stages chunk_base+lane*16B (coalesced)
// and the LDS image equals the MFMA fragment order -> conflict-free b128.

#define XBLKS 1024   // 4096*512 elems / 8 per thread / 256 threads
#define WBLKS 64

// ---------------- fused prep: split_x | split_wT | build_csr ----------------
__global__ __launch_bounds__(256) void k_prep(const float* __restrict__ x,
                                              const float* __restrict__ W,
                                              const float* __restrict__ adj,
                                              ushort* __restrict__ xhi,
                                              ushort* __restrict__ xlo,
                                              ushort* __restrict__ whiT,
                                              ushort* __restrict__ wloT,
                                              int* __restrict__ row_cnt,
                                              int* __restrict__ col_idx) {
    __shared__ float tile[64][65];
    __shared__ int cnt_s;
    int b = blockIdx.x;
    int t = threadIdx.x;
    if (b < XBLKS) {
        // ---- split x into bf16 hi/lo, staged layout (2 chunk-slots/thread) ----
        int tid = b * 256 + t;
        int rg = tid >> 9;              // 512 threads per 16-row group (8192 elems/16 rows /16 per thread... see below)
        // Each thread handles 8 elements: tid in [0, 262144). Chunk slot = tid.
        // Recompute exactly as round-4 k_split_x with tid in [0,262144):
        rg = tid >> 10;                 // wrong for 1024 blocks? No: 262144 slots/256 per rg-chunk-group
        int c  = tid & 1023;
        int kb = c >> 6;
        int l  = c & 63;
        int row = rg * 16 + (l & 15);
        int kbase = kb * 32 + (l >> 4) * 8;
        const float* src = &x[(size_t)row * F_IN + kbase];
        float4 v0 = *(const float4*)&src[0];
        float4 v1 = *(const float4*)&src[4];
        float f[8] = {v0.x, v0.y, v0.z, v0.w, v1.x, v1.y, v1.z, v1.w};
        us8 hv, lv;
#pragma unroll
        for (int u = 0; u < 8; ++u) {
            __bf16 h = (__bf16)f[u];
            __bf16 lo_ = (__bf16)(f[u] - (float)h);
            hv[u] = __builtin_bit_cast(unsigned short, h);
            lv[u] = __builtin_bit_cast(unsigned short, lo_);
        }
        *(us8*)&xhi[(size_t)tid * 8] = hv;
        *(us8*)&xlo[(size_t)tid * 8] = lv;
    } else if (b < XBLKS + WBLKS) {
        // ---- split + transpose W1 -> staged layout ----
        int bb = b - XBLKS;
        int n0 = (bb & 7) * 64, k0 = (bb >> 3) * 64;
#pragma unroll
        for (int i = 0; i < 4; ++i) {
            int r = i * 16 + (t >> 4);
            int c = (t & 15) * 4;
            *(float4*)&tile[r][c] = *(const float4*)&W[(size_t)(k0 + r) * HC + n0 + c];
        }
        __syncthreads();
        int rg_local = t >> 6;
        int l = t & 63;
        int n_local = rg_local * 16 + (l & 15);
#pragma unroll
        for (int kb_local = 0; kb_local < 2; ++kb_local) {
            int k_local = kb_local * 32 + (l >> 4) * 8;
            us8 hv, lv;
#pragma unroll
            for (int u = 0; u < 8; ++u) {
                float f = tile[k_local + u][n_local];
                __bf16 h = (__bf16)f;
                __bf16 lo_ = (__bf16)(f - (float)h);
                hv[u] = __builtin_bit_cast(unsigned short, h);
                lv[u] = __builtin_bit_cast(unsigned short, lo_);
            }
            int rg = (n0 >> 4) + rg_local;
            int kb = (k0 >> 5) + kb_local;
            size_t off = ((size_t)(rg * 16 + kb) * 64 + l) * 8;
            *(us8*)&whiT[off] = hv;
            *(us8*)&wloT[off] = lv;
        }
    } else {
        // ---- CSR build (adds self loop) ----
        int i = b - (XBLKS + WBLKS);
        if (t == 0) cnt_s = 0;
        __syncthreads();
        const float4* row = (const float4*)(adj + (size_t)i * N_NODES);
        int* cols = col_idx + (size_t)i * CAP;
#pragma unroll
        for (int it = 0; it < 4; ++it) {
            int idx4 = it * 256 + t;
            float4 v = row[idx4];
            int j0 = idx4 * 4;
            if (v.x != 0.f && j0 + 0 != i) { int p = atomicAdd(&cnt_s, 1); if (p < CAP - 1) cols[p] = j0 + 0; }
            if (v.y != 0.f && j0 + 1 != i) { int p = atomicAdd(&cnt_s, 1); if (p < CAP - 1) cols[p] = j0 + 1; }
            if (v.z != 0.f && j0 + 2 != i) { int p = atomicAdd(&cnt_s, 1); if (p < CAP - 1) cols[p] = j0 + 2; }
            if (v.w != 0.f && j0 + 3 != i) { int p = atomicAdd(&cnt_s, 1); if (p < CAP - 1) cols[p] = j0 + 3; }
        }
        __syncthreads();
        if (t == 0) {
            int p = min(cnt_s, CAP - 1);
            cols[p] = i;
            row_cnt[i] = p + 1;
        }
    }
}

// ---------------- GEMM1 (bf16 MFMA 3-pass) + fused attn scalars ----------------
__global__ __launch_bounds__(256) void k_gemm1(const ushort* __restrict__ Ahi,
                                               const ushort* __restrict__ Alo,
                                               const ushort* __restrict__ Bhi,
                                               const ushort* __restrict__ Blo,
                                               const float* __restrict__ att_src,
                                               const float* __restrict__ att_dst,
                                               __half* __restrict__ C,
                                               float* __restrict__ a_src,
                                               float* __restrict__ a_dst) {
    __shared__ __align__(16) ushort smem[4][2048];
    __shared__ float s_s[2][64], s_d[2][64];
    int t = threadIdx.x;
    int w = t >> 6, lane = t & 63;
    int n0 = blockIdx.x * 64;      // n-block == head blockIdx.x
    int m0 = blockIdx.y * 64;
    const ushort* src = (w == 0) ? Ahi : (w == 1) ? Alo : (w == 2) ? Bhi : Blo;
    int rg0 = ((w < 2) ? m0 : n0) >> 4;
    int mw = (w & 1) * 32, nw = (w >> 1) * 32;
    f32x4 acc[2][2] = {};
    for (int kb = 0; kb < 16; ++kb) {
#pragma unroll
        for (int g = 0; g < 4; ++g) {
            const ushort* gp = src + ((size_t)((rg0 + g) * 16 + kb) * 64 + lane) * 8;
            __builtin_amdgcn_global_load_lds(
                (const __attribute__((address_space(1))) void*)gp,
                (__attribute__((address_space(3))) void*)&smem[w][g * 512],
                16, 0, 0);
        }
        __syncthreads();
        bf16x8 ahi[2], alo[2], bhi[2], blo[2];
#pragma unroll
        for (int mi = 0; mi < 2; ++mi) {
            int g = (mw >> 4) + mi;
            ahi[mi] = __builtin_bit_cast(bf16x8, *(const us8*)&smem[0][g * 512 + lane * 8]);
            alo[mi] = __builtin_bit_cast(bf16x8, *(const us8*)&smem[1][g * 512 + lane * 8]);
        }
#pragma unroll
        for (int ni = 0; ni < 2; ++ni) {
            int g = (nw >> 4) + ni;
            bhi[ni] = __builtin_bit_cast(bf16x8, *(const us8*)&smem[2][g * 512 + lane * 8]);
            blo[ni] = __builtin_bit_cast(bf16x8, *(const us8*)&smem[3][g * 512 + lane * 8]);
        }
#pragma unroll
        for (int mi = 0; mi < 2; ++mi)
#pragma unroll
            for (int ni = 0; ni < 2; ++ni) {
                acc[mi][ni] = __builtin_amdgcn_mfma_f32_16x16x32_bf16(ahi[mi], bhi[ni], acc[mi][ni], 0, 0, 0);
                acc[mi][ni] = __builtin_amdgcn_mfma_f32_16x16x32_bf16(alo[mi], bhi[ni], acc[mi][ni], 0, 0, 0);
                acc[mi][ni] = __builtin_amdgcn_mfma_f32_16x16x32_bf16(ahi[mi], blo[ni], acc[mi][ni], 0, 0, 0);
            }
        __syncthreads();
    }
    int r0 = (lane >> 4) * 4;
    int cn = lane & 15;
    // fused attention scalars: per-row dot with att vectors (fp32 accs)
    float as0 = att_src[n0 + nw + cn],      as1 = att_src[n0 + nw + 16 + cn];
    float ad0 = att_dst[n0 + nw + cn],      ad1 = att_dst[n0 + nw + 16 + cn];
#pragma unroll
    for (int mi = 0; mi < 2; ++mi)
#pragma unroll
        for (int r = 0; r < 4; ++r) {
            float ps = acc[mi][0][r] * as0 + acc[mi][1][r] * as1;
            float pd = acc[mi][0][r] * ad0 + acc[mi][1][r] * ad1;
#pragma unroll
            for (int o = 1; o < 16; o <<= 1) {
                ps += __shfl_xor(ps, o, 64);
                pd += __shfl_xor(pd, o, 64);
            }
            if (cn == 0) {
                int row = mw + mi * 16 + r0 + r;
                s_s[w >> 1][row] = ps;
                s_d[w >> 1][row] = pd;
            }
        }
    // C store
#pragma unroll
    for (int mi = 0; mi < 2; ++mi)
#pragma unroll
        for (int ni = 0; ni < 2; ++ni) {
            size_t base = (size_t)(m0 + mw + mi * 16 + r0) * HC + (n0 + nw + ni * 16 + cn);
#pragma unroll
            for (int r = 0; r < 4; ++r)
                C[base + (size_t)r * HC] = __float2half(acc[mi][ni][r]);
        }
    __syncthreads();
    if (t < 64) {
        a_src[(m0 + t) * H_HEADS + blockIdx.x] = s_s[0][t] + s_s[1][t];
        a_dst[(m0 + t) * H_HEADS + blockIdx.x] = s_d[0][t] + s_d[1][t];
    }
}

// ---------------- layer-1 softmax aggregation + bias + ELU (fp16 out) ----------------
__global__ __launch_bounds__(256) void k_agg1(const __half* __restrict__ hf,
                                              const float* __restrict__ a_src,
                                              const float* __restrict__ a_dst,
                                              const int* __restrict__ row_cnt,
                                              const int* __restrict__ col_idx,
                                              const float* __restrict__ b1,
                                              __half* __restrict__ elu1) {
    int i = blockIdx.x;
    int t = threadIdx.x;
    __shared__ float wL[CAP][H_HEADS];
    __shared__ int   colL[CAP];
    __shared__ float denom[H_HEADS];
    __shared__ float ad[H_HEADS];
    int cnt = row_cnt[i];
    if (t < H_HEADS) ad[t] = a_dst[i * H_HEADS + t];
    for (int j = t; j < cnt; j += 256) colL[j] = col_idx[(size_t)i * CAP + j];
    __syncthreads();
    for (int idx = t; idx < cnt * H_HEADS; idx += 256) {
        int j = idx >> 3, h = idx & 7;
        float l = a_src[colL[j] * H_HEADS + h] + ad[h];
        l = (l > 0.f) ? l : NEG_SLOPE * l;
        wL[j][h] = __expf(l);
    }
    __syncthreads();
    {
        int h = t >> 5, l32 = t & 31;
        float s = 0.f;
        for (int j = l32; j < cnt; j += 32) s += wL[j][h];
#pragma unroll
        for (int o = 16; o > 0; o >>= 1) s += __shfl_down(s, o, 32);
        if (l32 == 0) denom[h] = s;
    }
    __syncthreads();
    int e = t * 2;
    int h = e >> 6;
    float ax = 0.f, ay = 0.f;
    int j = 0;
    for (; j + 4 <= cnt; j += 4) {
        int c0 = colL[j], c1 = colL[j + 1], c2 = colL[j + 2], c3 = colL[j + 3];
        float2 v0 = __half22float2(*(const __half2*)&hf[(size_t)c0 * HC + e]);
        float2 v1 = __half22float2(*(const __half2*)&hf[(size_t)c1 * HC + e]);
        float2 v2 = __half22float2(*(const __half2*)&hf[(size_t)c2 * HC + e]);
        float2 v3 = __half22float2(*(const __half2*)&hf[(size_t)c3 * HC + e]);
        float w0 = wL[j][h], w1 = wL[j + 1][h], w2 = wL[j + 2][h], w3 = wL[j + 3][h];
        ax += w0 * v0.x + w1 * v1.x + w2 * v2.x + w3 * v3.x;
        ay += w0 * v0.y + w1 * v1.y + w2 * v2.y + w3 * v3.y;
    }
    for (; j < cnt; ++j) {
        int c0 = colL[j];
        float2 v0 = __half22float2(*(const __half2*)&hf[(size_t)c0 * HC + e]);
        float w0 = wL[j][h];
        ax += w0 * v0.x;
        ay += w0 * v0.y;
    }
    float inv = 1.f / denom[h];
    float o0 = ax * inv + b1[e];
    float o1 = ay * inv + b1[e + 1];
    o0 = (o0 > 0.f) ? o0 : (__expf(o0) - 1.f);
    o1 = (o1 > 0.f) ? o1 : (__expf(o1) - 1.f);
    *(__half2*)&elu1[(size_t)i * HC + e] = __floats2half2_rn(o0, o1);
}

// ---------------- GEMM2 (16 nodes/block, W2 in LDS) + layer-2 scalars ----------------
__global__ __launch_bounds__(256) void k_gemm2(const __half* __restrict__ elu1,
                                               const float* __restrict__ W2,     // [512,16]
                                               const float* __restrict__ att_src2,
                                               const float* __restrict__ att_dst2,
                                               float* __restrict__ h2,
                                               float* __restrict__ a_src2,
                                               float* __restrict__ a_dst2) {
    __shared__ float W2s[HC * NCLS];   // 32 KB
    __shared__ float h2s[16][NCLS];
    int t = threadIdx.x;
    int n0 = blockIdx.x * 16;
#pragma unroll
    for (int u = 0; u < 8; ++u) {
        int idx = (u * 256 + t) * 4;
        *(float4*)&W2s[idx] = *(const float4*)&W2[idx];
    }
    __syncthreads();
    int nl = t >> 4, c = t & 15;
    const __half2* row = (const __half2*)(elu1 + (size_t)(n0 + nl) * HC);
    float acc = 0.f;
    for (int k = 0; k < HC; k += 4) {
        float2 v0 = __half22float2(row[k >> 1]);
        float2 v1 = __half22float2(row[(k >> 1) + 1]);
        acc += v0.x * W2s[(k + 0) * NCLS + c] + v0.y * W2s[(k + 1) * NCLS + c]
             + v1.x * W2s[(k + 2) * NCLS + c] + v1.y * W2s[(k + 3) * NCLS + c];
    }
    h2[(size_t)(n0 + nl) * NCLS + c] = acc;
    h2s[nl][c] = acc;
    __syncthreads();
    if (t < 16) {
        float s = 0.f, d = 0.f;
#pragma unroll
        for (int cc = 0; cc < NCLS; ++cc) {
            s += h2s[t][cc] * att_src2[cc];
            d += h2s[t][cc] * att_dst2[cc];
        }
        a_src2[n0 + t] = s;
        a_dst2[n0 + t] = d;
    }
}

// ---------------- layer-2 softmax aggregation ----------------
__global__ __launch_bounds__(256) void k_agg2(const float* __restrict__ h2,
                                              const float* __restrict__ a_src2,
                                              const float* __restrict__ a_dst2,
                                              const int* __restrict__ row_cnt,
                                              const int* __restrict__ col_idx,
                                              const float* __restrict__ b2,
                                              float* __restrict__ out) {
    int t = threadIdx.x;
    int w = t >> 6, lane = t & 63;
    int i = blockIdx.x * 4 + w;
    __shared__ float ew[4][CAP];
    __shared__ int   colL[4][CAP];
    int cnt = row_cnt[i];
    float adi = a_dst2[i];
    float sum = 0.f;
    for (int j = lane; j < cnt; j += 64) {
        int col = col_idx[(size_t)i * CAP + j];
        colL[w][j] = col;
        float l = a_src2[col] + adi;
        l = (l > 0.f) ? l : NEG_SLOPE * l;
        float e = __expf(l);
        ew[w][j] = e;
        sum += e;
    }
#pragma unroll
    for (int o = 32; o > 0; o >>= 1) sum += __shfl_xor(sum, o, 64);
    int q = lane >> 4, c = lane & 15;
    float acc = 0.f;
    for (int j = q; j < cnt; j += 4)
        acc += ew[w][j] * h2[(size_t)colL[w][j] * NCLS + c];
    acc += __shfl_down(acc, 32, 64);
    acc += __shfl_down(acc, 16, 64);
    if (lane < NCLS)
        out[(size_t)i * NCLS + lane] = acc / sum + b2[lane];
}

extern "C" void kernel_launch(void* const* d_in, const int* in_sizes, int n_in,
                              void* d_out, int out_size, void* d_ws, size_t ws_size,
                              hipStream_t stream) {
    const float* x        = (const float*)d_in[0];
    const float* adj      = (const float*)d_in[1];
    const float* W1       = (const float*)d_in[2];
    const float* att_src1 = (const float*)d_in[3];
    const float* att_dst1 = (const float*)d_in[4];
    const float* b1       = (const float*)d_in[5];
    const float* W2       = (const float*)d_in[6];
    const float* att_src2 = (const float*)d_in[7];
    const float* att_dst2 = (const float*)d_in[8];
    const float* b2       = (const float*)d_in[9];
    float* out = (float*)d_out;

    char* ws = (char*)d_ws;
    int*    row_cnt = (int*)ws;     ws += (size_t)N_NODES * 4;
    int*    col_idx = (int*)ws;     ws += (size_t)N_NODES * CAP * 4;
    __half* h1f     = (__half*)ws;  ws += (size_t)N_NODES * HC * 2;
    float*  a_src   = (float*)ws;   ws += (size_t)N_NODES * H_HEADS * 4;
    float*  a_dst   = (float*)ws;   ws += (size_t)N_NODES * H_HEADS * 4;
    __half* elu1    = (__half*)ws;  ws += (size_t)N_NODES * HC * 2;
    float*  h2      = (float*)ws;   ws += (size_t)N_NODES * NCLS * 4;
    float*  as2     = (float*)ws;   ws += (size_t)N_NODES * 4;
    float*  ad2     = (float*)ws;   ws += (size_t)N_NODES * 4;
    ushort* x_hi    = (ushort*)ws;  ws += (size_t)N_NODES * F_IN * 2;
    ushort* x_lo    = (ushort*)ws;  ws += (size_t)N_NODES * F_IN * 2;
    ushort* w_hiT   = (ushort*)ws;  ws += (size_t)F_IN * HC * 2;
    ushort* w_loT   = (ushort*)ws;  ws += (size_t)F_IN * HC * 2;

    hipLaunchKernelGGL(k_prep, dim3(XBLKS + WBLKS + N_NODES), dim3(256), 0, stream,
                       x, W1, adj, x_hi, x_lo, w_hiT, w_loT, row_cnt, col_idx);
    hipLaunchKernelGGL(k_gemm1, dim3(HC / 64, N_NODES / 64), dim3(256), 0, stream,
                       x_hi, x_lo, w_hiT, w_loT, att_src1, att_dst1, h1f, a_src, a_dst);
    hipLaunchKernelGGL(k_agg1, dim3(N_NODES), dim3(256), 0, stream,
                       h1f, a_src, a_dst, row_cnt, col_idx, b1, elu1);
    hipLaunchKernelGGL(k_gemm2, dim3(N_NODES / 16), dim3(256), 0, stream,
                       elu1, W2, att_src2, att_dst2, h2, as2, ad2);
    hipLaunchKernelGGL(k_agg2, dim3(N_NODES / 4), dim3(256), 0, stream,
                       h2, as2, ad2, row_cnt, col_idx, b2, out);
}